// Round 13
// baseline (645.271 us; speedup 1.0000x reference)
//
#include <hip/hip_runtime.h>
#include <math.h>

#define NBG 300
#define KP 8256   // K = 64*128 (i,h) + 64 bias rows

typedef __attribute__((ext_vector_type(8))) short short8_t;
typedef __attribute__((ext_vector_type(4))) float f32x4_t;

#define MFMA16(a,b,c) __builtin_amdgcn_mfma_f32_16x16x32_bf16(a,b,c,0,0,0)

__device__ __forceinline__ float sigmoidf_(float x){ return 1.0f/(1.0f+expf(-x)); }
__device__ __forceinline__ float bf2f(short s){
  union{unsigned u; float f;} v; v.u = ((unsigned)(unsigned short)s) << 16; return v.f;
}
__device__ __forceinline__ short f2bf(float f){
  union{float f; unsigned u;} v; v.f = f;
  unsigned r = (v.u + 0x7fffu + ((v.u >> 16) & 1u)) >> 16;
  return (short)r;
}
__device__ __forceinline__ unsigned cvt_pk_bf16(float lo, float hi){
  unsigned r;
  asm volatile("v_cvt_pk_bf16_f32 %0, %1, %2" : "=v"(r) : "v"(lo), "v"(hi));
  return r;
}
union FragA { short8_t v; unsigned u[4]; };

// products of packed-bf16 h row-slice with scalar sv -> bf16 A-frag
__device__ __forceinline__ short8_t frag_from(float sv, short8_t h){
  union { short8_t v; unsigned u[4]; } hh; hh.v = h;
  FragA fa;
  #pragma unroll
  for (int k2 = 0; k2 < 4; ++k2){
    float lo = __uint_as_float(hh.u[k2] << 16);
    float hi = __uint_as_float(hh.u[k2] & 0xffff0000u);
    fa.u[k2] = cvt_pk_bf16(sv*lo, sv*hi);
  }
  return fa.v;
}

// ---------- lin0 ----------
__global__ void lin0_kernel(const float* __restrict__ x, const float* __restrict__ w,
                            const float* __restrict__ b, float* __restrict__ out,
                            short* __restrict__ out_bf, int N){
  int n = blockIdx.x; int d = threadIdx.x;
  __shared__ float xs[16];
  if (d < 14) xs[d] = x[n*14 + d];
  __syncthreads();
  float acc = b[d];
  #pragma unroll
  for (int k = 0; k < 14; ++k) acc = fmaf(xs[k], w[d*14 + k], acc);
  float v = fmaxf(acc, 0.0f);
  out[n*64 + d] = v;
  out_bf[n*64 + d] = f2bf(v);
}

// ---------- edge MLP hidden (bf16 out) ----------
__global__ void ehid_kernel(const float* __restrict__ ea, const float* __restrict__ w,
                            const float* __restrict__ b, short* __restrict__ hid_bf, int E){
  int e = blockIdx.x; int t = threadIdx.x;
  __shared__ float as[4];
  if (t < 4) as[t] = ea[e*4 + t];
  __syncthreads();
  float acc = b[t];
  #pragma unroll
  for (int k = 0; k < 4; ++k) acc = fmaf(as[k], w[t*4 + k], acc);
  hid_bf[(size_t)e*128 + t] = f2bf(fmaxf(acc, 0.0f));
}

// ---------- combined counting (edge dst + node batch) ----------
__global__ void count2_kernel(const int* __restrict__ dstv, int E,
                              const int* __restrict__ batch, int N,
                              int* __restrict__ counts, int* __restrict__ bcounts){
  int i = blockIdx.x*blockDim.x + threadIdx.x;
  if (i < E) atomicAdd(&counts[dstv[i]], 1);
  int j = i - E;
  if (j >= 0 && j < N) atomicAdd(&bcounts[batch[j]], 1);
}

// ---------- scan (2 independent scans, one per block) ----------
__global__ __launch_bounds__(1024) void scan2_kernel(
    const int* __restrict__ countsA, int* __restrict__ startsA, int* __restrict__ cursorA, int NA,
    const int* __restrict__ countsB, int* __restrict__ startsB, int* __restrict__ cursorB, int NB){
  const int* counts = blockIdx.x ? countsB : countsA;
  int* starts = blockIdx.x ? startsB : startsA;
  int* cursor = blockIdx.x ? cursorB : cursorA;
  int N = blockIdx.x ? NB : NA;
  __shared__ int part[1024];
  int t = threadIdx.x;
  int per = (N + 1023) >> 10;
  int base = t * per;
  int s = 0;
  for (int j = 0; j < per; ++j){ int idx = base + j; if (idx < N) s += counts[idx]; }
  part[t] = s;
  __syncthreads();
  for (int off = 1; off < 1024; off <<= 1){
    int v = (t >= off) ? part[t - off] : 0;
    __syncthreads();
    part[t] += v;
    __syncthreads();
  }
  int run = (t == 0) ? 0 : part[t-1];
  for (int j = 0; j < per; ++j){
    int idx = base + j;
    if (idx < N){ starts[idx] = run; cursor[idx] = run; run += counts[idx]; }
  }
}

__global__ void scatter_kernel(const int* __restrict__ dst, int* __restrict__ cursor,
                               int* __restrict__ sorted_eid, int E){
  int e = blockIdx.x*blockDim.x + threadIdx.x;
  if (e < E){ int p = atomicAdd(&cursor[dst[e]], 1); sorted_eid[p] = e; }
}

// ---------- W2t build ----------
__global__ void w2t_build(const float* __restrict__ w2, const float* __restrict__ b2,
                          short* __restrict__ W2t){
  int o = blockIdx.x;
  for (int k = threadIdx.x; k < KP; k += blockDim.x){
    float val;
    if (k < 8192){ int i = k >> 7, h = k & 127; val = w2[(size_t)(i*64 + o)*128 + h]; }
    else val = b2[(k - 8192)*64 + o];
    W2t[(size_t)o*KP + k] = f2bf(val);
  }
}

// ---------- fused message GEMM + scatter, v7: register-B, barrier-free ----------
// 256 threads (4 waves), 128 edges/block, M=32 edges/wave, K-split 4.
// B fragments gathered straight from W2t (L2-resident) into a 4-phase
// register ring (prefetch distance = 4 chunks). No LDS for B, no barriers
// in the hot loop -> waves pipeline independently.
__global__ __launch_bounds__(256) void msg_gemm7(
    const short* __restrict__ out_bf, const short* __restrict__ hid_bf,
    const short* __restrict__ W2t, const int* __restrict__ sorted,
    const int* __restrict__ src, const int* __restrict__ dstv,
    float* __restrict__ agg, int E)
{
  __shared__ short sSb[128*80];                       // bf16 src rows, stride 80
  __shared__ int eid_s[128];
  __shared__ int dst_s[128];

  const int tid = threadIdx.x;
  const int blk = blockIdx.x;
  const int split = blockIdx.y;                       // 0..3

  if (tid < 128){
    int p = blk*128 + tid;
    int e = (p < E) ? sorted[p] : -1;
    eid_s[tid] = e;
    dst_s[tid] = (e >= 0) ? dstv[e] : -1;
  }
  __syncthreads();

  const int lane = tid & 63, wid = tid >> 6;
  const int r = lane & 15, q4 = lane >> 4;
  const int eloc0 = wid*32 + r;
  const int eloc1 = eloc0 + 16;

  short8_t z8 = {0,0,0,0,0,0,0,0};

  // stage s rows (bf16), row = tid>>1, half = tid&1
  {
    int row = tid >> 1, half = tid & 1;
    int e = eid_s[row];
    short* dp = sSb + row*80 + half*32;
    if (e >= 0){
      const short* sp = out_bf + (size_t)src[e]*64 + half*32;
      *(short8_t*)(dp)      = *(const short8_t*)(sp);
      *(short8_t*)(dp + 8)  = *(const short8_t*)(sp + 8);
      *(short8_t*)(dp + 16) = *(const short8_t*)(sp + 16);
      *(short8_t*)(dp + 24) = *(const short8_t*)(sp + 24);
    } else {
      *(short8_t*)(dp) = z8; *(short8_t*)(dp + 8) = z8;
      *(short8_t*)(dp + 16) = z8; *(short8_t*)(dp + 24) = z8;
    }
  }

  // h quarters, packed bf16 in regs (2 edges x 4 quarters)
  short8_t hq0_0=z8, hq0_1=z8, hq0_2=z8, hq0_3=z8;
  short8_t hq1_0=z8, hq1_1=z8, hq1_2=z8, hq1_3=z8;
  {
    int e0 = eid_s[eloc0], e1 = eid_s[eloc1];
    if (e0 >= 0){
      const short* hp = hid_bf + (size_t)e0*128 + q4*8;
      hq0_0 = *(const short8_t*)(hp);      hq0_1 = *(const short8_t*)(hp + 32);
      hq0_2 = *(const short8_t*)(hp + 64); hq0_3 = *(const short8_t*)(hp + 96);
    }
    if (e1 >= 0){
      const short* hp = hid_bf + (size_t)e1*128 + q4*8;
      hq1_0 = *(const short8_t*)(hp);      hq1_1 = *(const short8_t*)(hp + 32);
      hq1_2 = *(const short8_t*)(hp + 64); hq1_3 = *(const short8_t*)(hp + 96);
    }
  }

  // B gather base pointers: lane (r,q4) reads rows {r,16+r,32+r,48+r}, k-group q4
  const short* w2p0 = W2t + (size_t)(r)      *KP + q4*8;
  const short* w2p1 = W2t + (size_t)(16 + r) *KP + q4*8;
  const short* w2p2 = W2t + (size_t)(32 + r) *KP + q4*8;
  const short* w2p3 = W2t + (size_t)(48 + r) *KP + q4*8;

#define BLOAD(P, c_)                                                            \
  do { size_t kb = (size_t)(c_)*32;                                             \
    P##_0 = *(const short8_t*)(w2p0 + kb);                                      \
    P##_1 = *(const short8_t*)(w2p1 + kb);                                      \
    P##_2 = *(const short8_t*)(w2p2 + kb);                                      \
    P##_3 = *(const short8_t*)(w2p3 + kb); } while (0)

  const int cstart = split * 64;                      // 64 steady chunks/split

  short8_t B0_0=z8,B0_1=z8,B0_2=z8,B0_3=z8;
  short8_t B1_0=z8,B1_1=z8,B1_2=z8,B1_3=z8;
  short8_t B2_0=z8,B2_1=z8,B2_2=z8,B2_3=z8;
  short8_t B3_0=z8,B3_1=z8,B3_2=z8,B3_3=z8;
  BLOAD(B0, cstart + 0);
  BLOAD(B1, cstart + 1);
  BLOAD(B2, cstart + 2);
  BLOAD(B3, cstart + 3);

  __syncthreads();   // sSb ready; only barrier before scatter

  f32x4_t zz = {0.f,0.f,0.f,0.f};
  f32x4_t acc0 = zz, acc1 = zz, acc2 = zz, acc3 = zz;
  f32x4_t acc4 = zz, acc5 = zz, acc6 = zz, acc7 = zz;

#define QSTEP(P, H0, H1, QI, Q)                                                 \
  {                                                                             \
    short8_t f0 = frag_from(sv0, H0);                                           \
    short8_t f1 = frag_from(sv1, H1);                                           \
    acc0 = MFMA16(f0, P##_0, acc0);                                             \
    acc1 = MFMA16(f0, P##_1, acc1);                                             \
    acc2 = MFMA16(f0, P##_2, acc2);                                             \
    acc3 = MFMA16(f0, P##_3, acc3);                                             \
    acc4 = MFMA16(f1, P##_0, acc4);                                             \
    acc5 = MFMA16(f1, P##_1, acc5);                                             \
    acc6 = MFMA16(f1, P##_2, acc6);                                             \
    acc7 = MFMA16(f1, P##_3, acc7);                                             \
    if ((QI) < 15) BLOAD(P, cstart + ((QI)+1)*4 + (Q));                         \
  }

  #pragma unroll 1
  for (int qi = 0; qi < 16; ++qi){
    int qg = (split << 4) + qi;
    float sv0 = bf2f(sSb[eloc0*80 + qg]);
    float sv1 = bf2f(sSb[eloc1*80 + qg]);
    QSTEP(B0, hq0_0, hq1_0, qi, 0)
    QSTEP(B1, hq0_1, hq1_1, qi, 1)
    QSTEP(B2, hq0_2, hq1_2, qi, 2)
    QSTEP(B3, hq0_3, hq1_3, qi, 3)
  }

  if (split == 3){
    // bias chunks 256, 257; A = s-values directly (bf16 in sSb)
    BLOAD(B0, 256);
    BLOAD(B1, 257);
    #pragma unroll
    for (int tc = 0; tc < 2; ++tc){
      short8_t f0 = *(const short8_t*)(sSb + eloc0*80 + tc*32 + q4*8);
      short8_t f1 = *(const short8_t*)(sSb + eloc1*80 + tc*32 + q4*8);
      if (tc == 0){
        acc0 = MFMA16(f0, B0_0, acc0);
        acc1 = MFMA16(f0, B0_1, acc1);
        acc2 = MFMA16(f0, B0_2, acc2);
        acc3 = MFMA16(f0, B0_3, acc3);
        acc4 = MFMA16(f1, B0_0, acc4);
        acc5 = MFMA16(f1, B0_1, acc5);
        acc6 = MFMA16(f1, B0_2, acc6);
        acc7 = MFMA16(f1, B0_3, acc7);
      } else {
        acc0 = MFMA16(f0, B1_0, acc0);
        acc1 = MFMA16(f0, B1_1, acc1);
        acc2 = MFMA16(f0, B1_2, acc2);
        acc3 = MFMA16(f0, B1_3, acc3);
        acc4 = MFMA16(f1, B1_0, acc4);
        acc5 = MFMA16(f1, B1_1, acc5);
        acc6 = MFMA16(f1, B1_2, acc6);
        acc7 = MFMA16(f1, B1_3, acc7);
      }
    }
  }

  // scatter with run-merge over sorted consecutive dst (2 edge sub-tiles)
  {
    int ebase = wid*32 + q4*4;
    float c0 = 0.f, c1 = 0.f, c2 = 0.f, c3 = 0.f;
    #pragma unroll
    for (int reg = 0; reg < 4; ++reg){
      c0 += acc0[reg]; c1 += acc1[reg]; c2 += acc2[reg]; c3 += acc3[reg];
      int d = dst_s[ebase + reg];
      int dn = (reg < 3) ? dst_s[ebase + reg + 1] : -2;
      if (d != dn){
        if (d >= 0){
          float* ap = agg + (size_t)d*64;
          atomicAdd(ap + r,      c0);
          atomicAdd(ap + 16 + r, c1);
          atomicAdd(ap + 32 + r, c2);
          atomicAdd(ap + 48 + r, c3);
        }
        c0 = c1 = c2 = c3 = 0.f;
      }
    }
  }
  {
    int ebase = wid*32 + 16 + q4*4;
    float c0 = 0.f, c1 = 0.f, c2 = 0.f, c3 = 0.f;
    #pragma unroll
    for (int reg = 0; reg < 4; ++reg){
      c0 += acc4[reg]; c1 += acc5[reg]; c2 += acc6[reg]; c3 += acc7[reg];
      int d = dst_s[ebase + reg];
      int dn = (reg < 3) ? dst_s[ebase + reg + 1] : -2;
      if (d != dn){
        if (d >= 0){
          float* ap = agg + (size_t)d*64;
          atomicAdd(ap + r,      c0);
          atomicAdd(ap + 16 + r, c1);
          atomicAdd(ap + 32 + r, c2);
          atomicAdd(ap + 48 + r, c3);
        }
        c0 = c1 = c2 = c3 = 0.f;
      }
    }
  }
#undef QSTEP
#undef BLOAD
}

// ---------- node update (MFMA): M = relu(H@root_w + agg/deg + cb); GRU ----------
// Also zeroes agg after reading it (saves a memset launch per iteration).
__global__ __launch_bounds__(256) void node_mfma(
    const short* __restrict__ out_bf, float* __restrict__ agg,
    const int* __restrict__ counts,
    const float* __restrict__ root_w, const float* __restrict__ conv_b,
    const float* __restrict__ gwih, const float* __restrict__ gwhh,
    const float* __restrict__ gbih, const float* __restrict__ gbhh,
    float* __restrict__ out, short* __restrict__ out_bf_w,
    float* __restrict__ out_dup, int N)
{
  __shared__ short XH[64*128];
  __shared__ short rootT[64*64];
  __shared__ short Wih_s[192*64];
  __shared__ short Whh_s[192*64];
  __shared__ float rdeg_s[64];
  __shared__ float cb_s[64];

  int tid = threadIdx.x;
  int blk = blockIdx.x;
  int nbase = blk*64;

  {
    int n = tid >> 2, cq = tid & 3;
    int ng = nbase + n;
    short8_t v0 = {0,0,0,0,0,0,0,0}, v1 = v0;
    if (ng < N){
      const short* p = out_bf + (size_t)ng*64;
      v0 = *(const short8_t*)(p + cq*16);
      v1 = *(const short8_t*)(p + cq*16 + 8);
    }
    int c0 = 8 + cq*2;
    *(short8_t*)(XH + n*128 + ((c0     ^ (n & 7))*8)) = v0;
    *(short8_t*)(XH + n*128 + (((c0+1) ^ (n & 7))*8)) = v1;
  }
  {
    int i = tid >> 2, dq = tid & 3;
    #pragma unroll
    for (int j = 0; j < 16; ++j){
      int d = dq*16 + j;
      short v = f2bf(root_w[i*64 + d]);
      rootT[d*64 + (((i >> 3) ^ (d & 7))*8) + (i & 7)] = v;
    }
  }
  if (tid < 192){
    int g = tid;
    short pk[8];
    #pragma unroll
    for (int c = 0; c < 8; ++c){
      #pragma unroll
      for (int j = 0; j < 8; ++j) pk[j] = f2bf(gwih[g*64 + c*8 + j]);
      *(short8_t*)(Wih_s + g*64 + ((c ^ (g & 7))*8)) = *(short8_t*)&pk[0];
    }
    #pragma unroll
    for (int c = 0; c < 8; ++c){
      #pragma unroll
      for (int j = 0; j < 8; ++j) pk[j] = f2bf(gwhh[g*64 + c*8 + j]);
      *(short8_t*)(Whh_s + g*64 + ((c ^ (g & 7))*8)) = *(short8_t*)&pk[0];
    }
  }
  if (tid < 64){
    int ng = nbase + tid;
    int c = (ng < N) ? counts[ng] : 1;
    rdeg_s[tid] = 1.0f / fmaxf((float)c, 1.0f);
    cb_s[tid] = conv_b[tid];
  }
  __syncthreads();

  int lane = tid & 63, wid = tid >> 6;
  int r = lane & 15, q4 = lane >> 4;

  {
    int mh = (wid >> 1)*32, nh = (wid & 1)*32;
    f32x4_t z4 = {0.f,0.f,0.f,0.f};
    f32x4_t c00 = z4, c01 = z4, c10 = z4, c11 = z4;
    #pragma unroll
    for (int ks = 0; ks < 2; ++ks){
      int ck = 8 + ks*4 + q4;
      int swA = (ck ^ (r & 7))*8;
      int swB = ((ks*4 + q4) ^ (r & 7))*8;
      short8_t a0 = *(const short8_t*)(XH + (mh + r)*128 + swA);
      short8_t a1 = *(const short8_t*)(XH + (mh + 16 + r)*128 + swA);
      short8_t b0 = *(const short8_t*)(rootT + (nh + r)*64 + swB);
      short8_t b1 = *(const short8_t*)(rootT + (nh + 16 + r)*64 + swB);
      c00 = MFMA16(a0, b0, c00);
      c01 = MFMA16(a0, b1, c01);
      c10 = MFMA16(a1, b0, c10);
      c11 = MFMA16(a1, b1, c11);
    }
    #pragma unroll
    for (int mm = 0; mm < 2; ++mm){
      #pragma unroll
      for (int nn = 0; nn < 2; ++nn){
        f32x4_t cc = mm == 0 ? (nn == 0 ? c00 : c01) : (nn == 0 ? c10 : c11);
        int d = nh + nn*16 + r;
        #pragma unroll
        for (int reg = 0; reg < 4; ++reg){
          int n = mh + mm*16 + q4*4 + reg;
          int ng = nbase + n;
          float av = 0.0f;
          if (ng < N){
            av = agg[(size_t)ng*64 + d];
            agg[(size_t)ng*64 + d] = 0.0f;       // pre-zero for next msg pass
          }
          float v = cc[reg] + av * rdeg_s[n] + cb_s[d];
          v = fmaxf(v, 0.0f);
          XH[n*128 + (((d >> 3) ^ (n & 7))*8) + (d & 7)] = f2bf(v);
        }
      }
    }
  }
  __syncthreads();

  f32x4_t ax[4][3], ah[4][3];
  {
    f32x4_t z4 = {0.f,0.f,0.f,0.f};
    #pragma unroll
    for (int mt = 0; mt < 4; ++mt)
      #pragma unroll
      for (int gt = 0; gt < 3; ++gt){ ax[mt][gt] = z4; ah[mt][gt] = z4; }
  }
  #pragma unroll
  for (int ks = 0; ks < 2; ++ks){
    int ckM = ks*4 + q4;
    int ckH = 8 + ks*4 + q4;
    int swM = (ckM ^ (r & 7))*8;
    int swH = (ckH ^ (r & 7))*8;
    int swB = ((ks*4 + q4) ^ (r & 7))*8;
    short8_t bx[3], bh[3];
    #pragma unroll
    for (int gt = 0; gt < 3; ++gt){
      int g = gt*64 + wid*16 + r;
      bx[gt] = *(const short8_t*)(Wih_s + g*64 + swB);
      bh[gt] = *(const short8_t*)(Whh_s + g*64 + swB);
    }
    #pragma unroll
    for (int mt = 0; mt < 4; ++mt){
      short8_t aM = *(const short8_t*)(XH + (mt*16 + r)*128 + swM);
      short8_t aH = *(const short8_t*)(XH + (mt*16 + r)*128 + swH);
      #pragma unroll
      for (int gt = 0; gt < 3; ++gt){
        ax[mt][gt] = MFMA16(aM, bx[gt], ax[mt][gt]);
        ah[mt][gt] = MFMA16(aH, bh[gt], ah[mt][gt]);
      }
    }
  }

  {
    int d = wid*16 + r;
    float bir = gbih[d],      bhr = gbhh[d];
    float biz = gbih[64 + d], bhz = gbhh[64 + d];
    float bin_ = gbih[128 + d], bhn = gbhh[128 + d];
    #pragma unroll
    for (int mt = 0; mt < 4; ++mt){
      #pragma unroll
      for (int reg = 0; reg < 4; ++reg){
        int n = mt*16 + q4*4 + reg;
        int ng = nbase + n;
        if (ng < N){
          float gxr = ax[mt][0][reg], gxz = ax[mt][1][reg], gxn = ax[mt][2][reg];
          float ghr = ah[mt][0][reg], ghz = ah[mt][1][reg], ghn = ah[mt][2][reg];
          float rr = sigmoidf_(gxr + ghr + bir + bhr);
          float zz = sigmoidf_(gxz + ghz + biz + bhz);
          float nn = tanhf(gxn + bin_ + rr*(ghn + bhn));
          float h = out[(size_t)ng*64 + d];
          float v = (1.0f - zz)*nn + zz*h;
          out[(size_t)ng*64 + d] = v;
          out_bf_w[(size_t)ng*64 + d] = f2bf(v);
          if (out_dup) out_dup[(size_t)ng*64 + d] = v;
        }
      }
    }
  }
}

// ---------- Set2Set (3 steps) + readout, 256 threads, node-parallel ----------
__global__ __launch_bounds__(256) void set2set_kernel(
    const float* __restrict__ out, const int* __restrict__ bstarts,
    const int* __restrict__ bcounts,
    const float* __restrict__ lwih, const float* __restrict__ lwhh,
    const float* __restrict__ lbih, const float* __restrict__ lbhh,
    const float* __restrict__ l1w, const float* __restrict__ l1b,
    const float* __restrict__ l2w, const float* __restrict__ l2b,
    float* __restrict__ y)
{
  int b = blockIdx.x, t = threadIdx.x;
  int lane = t & 63, wid = t >> 6;
  __shared__ float qs[128];
  __shared__ float hsl[64], hs_s[64], cs_s[64];
  __shared__ float ev[512];
  __shared__ float red[256];
  __shared__ float rpart[4][64];
  __shared__ float scal[2];

  int s0 = bstarts[b], cnt = bcounts[b];
  if (cnt > 512) cnt = 512;
  if (t < 64){ hs_s[t] = 0.f; cs_s[t] = 0.f; }
  if (t < 128) qs[t] = 0.f;
  __syncthreads();

  for (int step = 0; step < 3; ++step){
    if (t < 64) hsl[t] = hs_s[t];
    __syncthreads();
    {
      float a0 = lbih[t] + lbhh[t], a1 = 0.f, a2 = 0.f, a3 = 0.f;
      const float* wi = lwih + t*128;
      #pragma unroll
      for (int kq = 0; kq < 32; ++kq){
        float4 w4 = *(const float4*)(wi + kq*4);
        a0 = fmaf(qs[kq*4+0], w4.x, a0);
        a1 = fmaf(qs[kq*4+1], w4.y, a1);
        a2 = fmaf(qs[kq*4+2], w4.z, a2);
        a3 = fmaf(qs[kq*4+3], w4.w, a3);
      }
      const float* wh = lwhh + t*64;
      #pragma unroll
      for (int kq = 0; kq < 16; ++kq){
        float4 w4 = *(const float4*)(wh + kq*4);
        a0 = fmaf(hsl[kq*4+0], w4.x, a0);
        a1 = fmaf(hsl[kq*4+1], w4.y, a1);
        a2 = fmaf(hsl[kq*4+2], w4.z, a2);
        a3 = fmaf(hsl[kq*4+3], w4.w, a3);
      }
      red[t] = (a0 + a1) + (a2 + a3);
    }
    __syncthreads();
    if (t < 64){
      float ig = sigmoidf_(red[t]);
      float fg = sigmoidf_(red[64 + t]);
      float gg = tanhf(red[128 + t]);
      float og = sigmoidf_(red[192 + t]);
      float c = fg*cs_s[t] + ig*gg;
      cs_s[t] = c;
      hs_s[t] = og*tanhf(c);
    }
    __syncthreads();

    float lmax = -1e30f;
    for (int idx = t; idx < cnt; idx += 256){
      const float* row = out + (size_t)(s0 + idx)*64;
      float a0 = 0.f, a1 = 0.f, a2 = 0.f, a3 = 0.f;
      #pragma unroll
      for (int kq = 0; kq < 16; ++kq){
        float4 v = *(const float4*)(row + kq*4);
        a0 = fmaf(v.x, hs_s[kq*4+0], a0);
        a1 = fmaf(v.y, hs_s[kq*4+1], a1);
        a2 = fmaf(v.z, hs_s[kq*4+2], a2);
        a3 = fmaf(v.w, hs_s[kq*4+3], a3);
      }
      float acc = (a0 + a1) + (a2 + a3);
      ev[idx] = acc;
      lmax = fmaxf(lmax, acc);
    }
    red[t] = lmax;
    __syncthreads();
    #pragma unroll
    for (int off = 128; off > 0; off >>= 1){
      if (t < off) red[t] = fmaxf(red[t], red[t + off]);
      __syncthreads();
    }
    if (t == 0) scal[0] = red[0];
    __syncthreads();
    float m = scal[0];

    float ls = 0.f;
    for (int idx = t; idx < cnt; idx += 256){
      float a = expf(ev[idx] - m);
      ev[idx] = a;
      ls += a;
    }
    red[t] = ls;
    __syncthreads();
    #pragma unroll
    for (int off = 128; off > 0; off >>= 1){
      if (t < off) red[t] += red[t + off];
      __syncthreads();
    }
    if (t == 0) scal[1] = red[0];
    __syncthreads();
    float lst = scal[1];

    float part = 0.f;
    for (int idx = wid; idx < cnt; idx += 4)
      part = fmaf(ev[idx], out[(size_t)(s0 + idx)*64 + lane], part);
    rpart[wid][lane] = part;
    __syncthreads();
    if (t < 64){
      float r = (rpart[0][t] + rpart[1][t]) + (rpart[2][t] + rpart[3][t]);
      r = (cnt > 0) ? r / lst : 0.f;
      qs[t] = hs_s[t];
      qs[64 + t] = r;
    }
    __syncthreads();
  }

  if (t < 64){
    float a0 = l1b[t], a1 = 0.f, a2 = 0.f, a3 = 0.f;
    const float* w1 = l1w + t*128;
    #pragma unroll
    for (int kq = 0; kq < 32; ++kq){
      float4 w4 = *(const float4*)(w1 + kq*4);
      a0 = fmaf(qs[kq*4+0], w4.x, a0);
      a1 = fmaf(qs[kq*4+1], w4.y, a1);
      a2 = fmaf(qs[kq*4+2], w4.z, a2);
      a3 = fmaf(qs[kq*4+3], w4.w, a3);
    }
    float acc = (a0 + a1) + (a2 + a3);
    float v = fmaxf(acc, 0.0f) * l2w[t];
    #pragma unroll
    for (int off = 32; off > 0; off >>= 1) v += __shfl_xor(v, off, 64);
    if (t == 0) y[b] = v + l2b[0];
  }
}

extern "C" void kernel_launch(void* const* d_in, const int* in_sizes, int n_in,
                              void* d_out, int out_size, void* d_ws, size_t ws_size,
                              hipStream_t stream){
  const float* x      = (const float*)d_in[0];
  const int*   ei     = (const int*)  d_in[1];
  const float* ea     = (const float*)d_in[2];
  const int*   batch  = (const int*)  d_in[3];
  const float* lin0_w = (const float*)d_in[4];
  const float* lin0_b = (const float*)d_in[5];
  const float* nn1_w  = (const float*)d_in[6];
  const float* nn1_b  = (const float*)d_in[7];
  const float* nn2_w  = (const float*)d_in[8];
  const float* nn2_b  = (const float*)d_in[9];
  const float* root_w = (const float*)d_in[10];
  const float* conv_b = (const float*)d_in[11];
  const float* gwih   = (const float*)d_in[12];
  const float* gwhh   = (const float*)d_in[13];
  const float* gbih   = (const float*)d_in[14];
  const float* gbhh   = (const float*)d_in[15];
  const float* lwih   = (const float*)d_in[16];
  const float* lwhh   = (const float*)d_in[17];
  const float* lbih   = (const float*)d_in[18];
  const float* lbhh   = (const float*)d_in[19];
  const float* l1w    = (const float*)d_in[20];
  const float* l1b    = (const float*)d_in[21];
  const float* l2w    = (const float*)d_in[22];
  const float* l2b    = (const float*)d_in[23];

  const int N = in_sizes[0] / 14;
  const int E = in_sizes[1] / 2;
  const int B = NBG;
  const int* src  = ei;
  const int* dstv = ei + E;

  char* wsp = (char*)d_ws; size_t off = 0;
  auto alloc = [&](size_t bytes)->char* {
    char* p = wsp + off; off += (bytes + 255) & ~((size_t)255); return p;
  };
  float* out     = (float*)alloc((size_t)N*64*4);
  short* out_bf  = (short*)alloc((size_t)N*64*2);
  float* agg     = (float*)alloc((size_t)N*64*4);
  int*   counts  = (int*)  alloc((size_t)N*4);
  int*   bcounts = (int*)  alloc((size_t)B*4);
  int*   starts  = (int*)  alloc((size_t)N*4);
  int*   cursor  = (int*)  alloc((size_t)N*4);
  int*   sorted  = (int*)  alloc((size_t)E*4);
  int*   bstarts = (int*)  alloc((size_t)B*4);
  int*   bcursor = (int*)  alloc((size_t)B*4);
  short* hid_bf  = (short*)alloc((size_t)E*128*2);
  short* W2t     = (short*)alloc((size_t)64*KP*2);

  lin0_kernel<<<N, 64, 0, stream>>>(x, lin0_w, lin0_b, out, out_bf, N);
  ehid_kernel<<<E, 128, 0, stream>>>(ea, nn1_w, nn1_b, hid_bf, E);

  size_t cspan = (((size_t)N*4 + 255) & ~(size_t)255) + (size_t)B*4;
  hipMemsetAsync(counts, 0, cspan, stream);
  count2_kernel<<<(E + N + 255)/256, 256, 0, stream>>>(dstv, E, batch, N, counts, bcounts);
  scan2_kernel<<<2, 1024, 0, stream>>>(counts, starts, cursor, N,
                                       bcounts, bstarts, bcursor, B);
  scatter_kernel<<<(E + 255)/256, 256, 0, stream>>>(dstv, cursor, sorted, E);

  w2t_build<<<64, 256, 0, stream>>>(nn2_w, nn2_b, W2t);
  hipMemsetAsync(agg, 0, (size_t)N*64*4, stream);

  int mblocks = (E + 127)/128;
  int nblocks = (N + 63)/64;
  dim3 mg(mblocks, 4);
  for (int it = 0; it < 3; ++it){
    msg_gemm7<<<mg, 256, 0, stream>>>(out_bf, hid_bf, W2t, sorted, src, dstv, agg, E);
    node_mfma<<<nblocks, 256, 0, stream>>>(out_bf, agg, counts, root_w, conv_b,
                                           gwih, gwhh, gbih, gbhh, out, out_bf,
                                           (it == 2) ? ((float*)d_out + 300) : nullptr, N);
  }

  set2set_kernel<<<B, 256, 0, stream>>>(out, bstarts, bcounts, lwih, lwhh, lbih, lbhh,
                                        l1w, l1b, l2w, l2b, (float*)d_out);
}

// Round 14
// 352.934 us; speedup vs baseline: 1.8283x; 1.8283x over previous
//
#include <hip/hip_runtime.h>
#include <math.h>

#define NBG 300
#define KP 8256   // K = 64*128 (i,h) + 64 bias rows

typedef __attribute__((ext_vector_type(8))) short short8_t;
typedef __attribute__((ext_vector_type(4))) float f32x4_t;

#define MFMA16(a,b,c) __builtin_amdgcn_mfma_f32_16x16x32_bf16(a,b,c,0,0,0)

__device__ __forceinline__ float sigmoidf_(float x){ return 1.0f/(1.0f+expf(-x)); }
__device__ __forceinline__ float bf2f(short s){
  union{unsigned u; float f;} v; v.u = ((unsigned)(unsigned short)s) << 16; return v.f;
}
__device__ __forceinline__ short f2bf(float f){
  union{float f; unsigned u;} v; v.f = f;
  unsigned r = (v.u + 0x7fffu + ((v.u >> 16) & 1u)) >> 16;
  return (short)r;
}
__device__ __forceinline__ unsigned cvt_pk_bf16(float lo, float hi){
  unsigned r;
  asm volatile("v_cvt_pk_bf16_f32 %0, %1, %2" : "=v"(r) : "v"(lo), "v"(hi));
  return r;
}
union FragA { short8_t v; unsigned u[4]; };

// products of packed-bf16 h row-slice with scalar sv -> bf16 A-frag
__device__ __forceinline__ short8_t frag_from(float sv, short8_t h){
  union { short8_t v; unsigned u[4]; } hh; hh.v = h;
  FragA fa;
  #pragma unroll
  for (int k2 = 0; k2 < 4; ++k2){
    float lo = __uint_as_float(hh.u[k2] << 16);
    float hi = __uint_as_float(hh.u[k2] & 0xffff0000u);
    fa.u[k2] = cvt_pk_bf16(sv*lo, sv*hi);
  }
  return fa.v;
}

// ---------- lin0 ----------
__global__ void lin0_kernel(const float* __restrict__ x, const float* __restrict__ w,
                            const float* __restrict__ b, float* __restrict__ out,
                            short* __restrict__ out_bf, int N){
  int n = blockIdx.x; int d = threadIdx.x;
  __shared__ float xs[16];
  if (d < 14) xs[d] = x[n*14 + d];
  __syncthreads();
  float acc = b[d];
  #pragma unroll
  for (int k = 0; k < 14; ++k) acc = fmaf(xs[k], w[d*14 + k], acc);
  float v = fmaxf(acc, 0.0f);
  out[n*64 + d] = v;
  out_bf[n*64 + d] = f2bf(v);
}

// ---------- edge MLP hidden (bf16 out) ----------
__global__ void ehid_kernel(const float* __restrict__ ea, const float* __restrict__ w,
                            const float* __restrict__ b, short* __restrict__ hid_bf, int E){
  int e = blockIdx.x; int t = threadIdx.x;
  __shared__ float as[4];
  if (t < 4) as[t] = ea[e*4 + t];
  __syncthreads();
  float acc = b[t];
  #pragma unroll
  for (int k = 0; k < 4; ++k) acc = fmaf(as[k], w[t*4 + k], acc);
  hid_bf[(size_t)e*128 + t] = f2bf(fmaxf(acc, 0.0f));
}

// ---------- combined counting (edge dst + node batch) ----------
__global__ void count2_kernel(const int* __restrict__ dstv, int E,
                              const int* __restrict__ batch, int N,
                              int* __restrict__ counts, int* __restrict__ bcounts){
  int i = blockIdx.x*blockDim.x + threadIdx.x;
  if (i < E) atomicAdd(&counts[dstv[i]], 1);
  int j = i - E;
  if (j >= 0 && j < N) atomicAdd(&bcounts[batch[j]], 1);
}

// ---------- scan (2 independent scans, one per block) ----------
__global__ __launch_bounds__(1024) void scan2_kernel(
    const int* __restrict__ countsA, int* __restrict__ startsA, int* __restrict__ cursorA, int NA,
    const int* __restrict__ countsB, int* __restrict__ startsB, int* __restrict__ cursorB, int NB){
  const int* counts = blockIdx.x ? countsB : countsA;
  int* starts = blockIdx.x ? startsB : startsA;
  int* cursor = blockIdx.x ? cursorB : cursorA;
  int N = blockIdx.x ? NB : NA;
  __shared__ int part[1024];
  int t = threadIdx.x;
  int per = (N + 1023) >> 10;
  int base = t * per;
  int s = 0;
  for (int j = 0; j < per; ++j){ int idx = base + j; if (idx < N) s += counts[idx]; }
  part[t] = s;
  __syncthreads();
  for (int off = 1; off < 1024; off <<= 1){
    int v = (t >= off) ? part[t - off] : 0;
    __syncthreads();
    part[t] += v;
    __syncthreads();
  }
  int run = (t == 0) ? 0 : part[t-1];
  for (int j = 0; j < per; ++j){
    int idx = base + j;
    if (idx < N){ starts[idx] = run; cursor[idx] = run; run += counts[idx]; }
  }
}

__global__ void scatter_kernel(const int* __restrict__ dst, int* __restrict__ cursor,
                               int* __restrict__ sorted_eid, int E){
  int e = blockIdx.x*blockDim.x + threadIdx.x;
  if (e < E){ int p = atomicAdd(&cursor[dst[e]], 1); sorted_eid[p] = e; }
}

// ---------- W2t build ----------
__global__ void w2t_build(const float* __restrict__ w2, const float* __restrict__ b2,
                          short* __restrict__ W2t){
  int o = blockIdx.x;
  for (int k = threadIdx.x; k < KP; k += blockDim.x){
    float val;
    if (k < 8192){ int i = k >> 7, h = k & 127; val = w2[(size_t)(i*64 + o)*128 + h]; }
    else val = b2[(k - 8192)*64 + o];
    W2t[(size_t)o*KP + k] = f2bf(val);
  }
}

// ---------- fused message GEMM + scatter, v3 structure, K-split 4 ----------
// 128 edges/block (32/wave). Chunk = K:32 for all 64 o (4096B). B staged by
// global_load_lds: linear LDS dest (tid*16B), SOURCE-swizzled so LDS position
// p (16B units) = o*4 + (kq ^ ((o>>1)&3)). Depth-3 counted-vmcnt pipeline.
__global__ __launch_bounds__(256) void msg_gemm3(
    const short* __restrict__ out_bf, const short* __restrict__ hid_bf,
    const short* __restrict__ W2t, const int* __restrict__ sorted,
    const int* __restrict__ src, const int* __restrict__ dstv,
    float* __restrict__ agg, int E)
{
  __shared__ short sSb[128*80];                       // bf16 src rows, stride 80
  __shared__ __align__(16) char bufB[4][4096];
  __shared__ int eid_s[128];
  __shared__ int dst_s[128];

  const int tid = threadIdx.x;
  const int blk = blockIdx.x;
  const int split = blockIdx.y;                       // 0..3

  if (tid < 128){
    int p = blk*128 + tid;
    int e = (p < E) ? sorted[p] : -1;
    eid_s[tid] = e;
    dst_s[tid] = (e >= 0) ? dstv[e] : -1;
  }
  __syncthreads();

  const int lane = tid & 63, wid = tid >> 6;
  const int r = lane & 15, q4 = lane >> 4;
  const int eloc0 = wid*32 + r;
  const int eloc1 = eloc0 + 16;

  short8_t z8 = {0,0,0,0,0,0,0,0};

  // stage s rows (bf16), row = tid>>1, half = tid&1
  {
    int row = tid >> 1, half = tid & 1;
    int e = eid_s[row];
    short* dp = sSb + row*80 + half*32;
    if (e >= 0){
      const short* sp = out_bf + (size_t)src[e]*64 + half*32;
      *(short8_t*)(dp)      = *(const short8_t*)(sp);
      *(short8_t*)(dp + 8)  = *(const short8_t*)(sp + 8);
      *(short8_t*)(dp + 16) = *(const short8_t*)(sp + 16);
      *(short8_t*)(dp + 24) = *(const short8_t*)(sp + 24);
    } else {
      *(short8_t*)(dp) = z8; *(short8_t*)(dp + 8) = z8;
      *(short8_t*)(dp + 16) = z8; *(short8_t*)(dp + 24) = z8;
    }
  }

  // h quarters, packed bf16 in regs (2 edges x 4 quarters)
  short8_t hq0_0=z8, hq0_1=z8, hq0_2=z8, hq0_3=z8;
  short8_t hq1_0=z8, hq1_1=z8, hq1_2=z8, hq1_3=z8;
  {
    int e0 = eid_s[eloc0], e1 = eid_s[eloc1];
    if (e0 >= 0){
      const short* hp = hid_bf + (size_t)e0*128 + q4*8;
      hq0_0 = *(const short8_t*)(hp);      hq0_1 = *(const short8_t*)(hp + 32);
      hq0_2 = *(const short8_t*)(hp + 64); hq0_3 = *(const short8_t*)(hp + 96);
    }
    if (e1 >= 0){
      const short* hp = hid_bf + (size_t)e1*128 + q4*8;
      hq1_0 = *(const short8_t*)(hp);      hq1_1 = *(const short8_t*)(hp + 32);
      hq1_2 = *(const short8_t*)(hp + 64); hq1_3 = *(const short8_t*)(hp + 96);
    }
  }

  // B staging: thread covers o-row gl_o, k-group gl_kq (8 shorts = 16B).
  // LDS dest is linear (tid*16B => position gl_o*4 + (tid&3)); pre-swizzled
  // source group gl_kq = (tid&3)^((tid>>3)&3) realizes the involution.
  const int gl_o  = tid >> 2;
  const int gl_kq = (tid & 3) ^ ((tid >> 3) & 3);
  const char* w2b = (const char*)W2t;
  const size_t gbase = (size_t)gl_o*(KP*2) + (size_t)gl_kq*16;

  // B-frag read byte offsets within a buf (content q4 at slot q4^((o>>1)&3))
  int boff0, boff1, boff2, boff3;
  {
    int o0 = r, o1 = 16 + r, o2 = 32 + r, o3 = 48 + r;
    boff0 = (o0*4 + (q4 ^ ((o0 >> 1) & 3))) * 16;
    boff1 = (o1*4 + (q4 ^ ((o1 >> 1) & 3))) * 16;
    boff2 = (o2*4 + (q4 ^ ((o2 >> 1) & 3))) * 16;
    boff3 = (o3*4 + (q4 ^ ((o3 >> 1) & 3))) * 16;
  }

  const bool last  = (split == 3);
  const int cstart = split * 64;                     // 64 chunks per split
  const int nc     = last ? 66 : 64;                 // split 3 takes bias chunks
  const int clast  = cstart + nc - 1;

#define GLOAD(c_, bi_)                                                          \
  __builtin_amdgcn_global_load_lds(                                             \
      (const __attribute__((address_space(1))) unsigned*)(w2b + gbase + (size_t)(c_)*64), \
      (__attribute__((address_space(3))) unsigned*)(&bufB[bi_][wid*1024]), 16, 0, 0)

  // prologue: prefetch chunks cstart..cstart+2 (cstart%4==0 => bufs 0,1,2)
  GLOAD(cstart + 0, (cstart + 0) & 3);
  GLOAD(cstart + 1, (cstart + 1) & 3);
  GLOAD(cstart + 2, (cstart + 2) & 3);
  __syncthreads();   // drains everything once; sS + bufs 0-2 ready

  f32x4_t zz = {0.f,0.f,0.f,0.f};
  f32x4_t acc00 = zz, acc01 = zz, acc02 = zz, acc03 = zz;
  f32x4_t acc10 = zz, acc11 = zz, acc12 = zz, acc13 = zz;

#define CHUNK(QI, Q, HQ0, HQ1)                                                  \
  {                                                                             \
    int c = cstart + (QI)*4 + (Q);                                              \
    asm volatile("s_waitcnt vmcnt(2) lgkmcnt(0)" ::: "memory");                 \
    __builtin_amdgcn_s_barrier();                                               \
    const char* bp = bufB[c & 3];                                               \
    short8_t b0 = *(const short8_t*)(bp + boff0);                               \
    short8_t b1 = *(const short8_t*)(bp + boff1);                               \
    short8_t b2 = *(const short8_t*)(bp + boff2);                               \
    short8_t b3 = *(const short8_t*)(bp + boff3);                               \
    { int cn = c + 3; if (cn > clast) cn = clast; GLOAD(cn, (c + 3) & 3); }     \
    short8_t f0 = frag_from(sv0, HQ0);                                          \
    short8_t f1 = frag_from(sv1, HQ1);                                          \
    acc00 = MFMA16(f0, b0, acc00);                                              \
    acc01 = MFMA16(f0, b1, acc01);                                              \
    acc02 = MFMA16(f0, b2, acc02);                                              \
    acc03 = MFMA16(f0, b3, acc03);                                              \
    acc10 = MFMA16(f1, b0, acc10);                                              \
    acc11 = MFMA16(f1, b1, acc11);                                              \
    acc12 = MFMA16(f1, b2, acc12);                                              \
    acc13 = MFMA16(f1, b3, acc13);                                              \
  }

  #pragma unroll 1
  for (int qi = 0; qi < 16; ++qi){
    int qg = (split << 4) + qi;                      // i value for this 4-chunk group
    float sv0 = bf2f(sSb[eloc0*80 + qg]);
    float sv1 = bf2f(sSb[eloc1*80 + qg]);
    CHUNK(qi, 0, hq0_0, hq1_0)
    CHUNK(qi, 1, hq0_1, hq1_1)
    CHUNK(qi, 2, hq0_2, hq1_2)
    CHUNK(qi, 3, hq0_3, hq1_3)
  }

  if (last){
    // bias tail: chunks 256 (buf 0), 257 (buf 1); A = s-values (bf16 in sSb)
    #pragma unroll 1
    for (int tc = 0; tc < 2; ++tc){
      int c = 256 + tc;
      asm volatile("s_waitcnt vmcnt(2) lgkmcnt(0)" ::: "memory");
      __builtin_amdgcn_s_barrier();
      const char* bp = bufB[c & 3];
      short8_t b0 = *(const short8_t*)(bp + boff0);
      short8_t b1 = *(const short8_t*)(bp + boff1);
      short8_t b2 = *(const short8_t*)(bp + boff2);
      short8_t b3 = *(const short8_t*)(bp + boff3);
      GLOAD(clast, (c + 3) & 3);
      short8_t f0 = *(const short8_t*)(sSb + eloc0*80 + tc*32 + q4*8);
      short8_t f1 = *(const short8_t*)(sSb + eloc1*80 + tc*32 + q4*8);
      acc00 = MFMA16(f0, b0, acc00);
      acc01 = MFMA16(f0, b1, acc01);
      acc02 = MFMA16(f0, b2, acc02);
      acc03 = MFMA16(f0, b3, acc03);
      acc10 = MFMA16(f1, b0, acc10);
      acc11 = MFMA16(f1, b1, acc11);
      acc12 = MFMA16(f1, b2, acc12);
      acc13 = MFMA16(f1, b3, acc13);
    }
  }

  asm volatile("s_waitcnt vmcnt(0)" ::: "memory");

  // scatter with run-merge over sorted consecutive dst (2 edge sub-tiles)
  {
    int ebase = wid*32 + q4*4;
    float c0 = 0.f, c1 = 0.f, c2 = 0.f, c3 = 0.f;
    #pragma unroll
    for (int reg = 0; reg < 4; ++reg){
      c0 += acc00[reg]; c1 += acc01[reg]; c2 += acc02[reg]; c3 += acc03[reg];
      int d = dst_s[ebase + reg];
      int dn = (reg < 3) ? dst_s[ebase + reg + 1] : -2;
      if (d != dn){
        if (d >= 0){
          float* ap = agg + (size_t)d*64;
          atomicAdd(ap + r,      c0);
          atomicAdd(ap + 16 + r, c1);
          atomicAdd(ap + 32 + r, c2);
          atomicAdd(ap + 48 + r, c3);
        }
        c0 = c1 = c2 = c3 = 0.f;
      }
    }
  }
  {
    int ebase = wid*32 + 16 + q4*4;
    float c0 = 0.f, c1 = 0.f, c2 = 0.f, c3 = 0.f;
    #pragma unroll
    for (int reg = 0; reg < 4; ++reg){
      c0 += acc10[reg]; c1 += acc11[reg]; c2 += acc12[reg]; c3 += acc13[reg];
      int d = dst_s[ebase + reg];
      int dn = (reg < 3) ? dst_s[ebase + reg + 1] : -2;
      if (d != dn){
        if (d >= 0){
          float* ap = agg + (size_t)d*64;
          atomicAdd(ap + r,      c0);
          atomicAdd(ap + 16 + r, c1);
          atomicAdd(ap + 32 + r, c2);
          atomicAdd(ap + 48 + r, c3);
        }
        c0 = c1 = c2 = c3 = 0.f;
      }
    }
  }
#undef CHUNK
#undef GLOAD
}

// ---------- node update (MFMA): M = relu(H@root_w + agg/deg + cb); GRU ----------
// Also zeroes agg after reading it (saves a memset launch per iteration).
__global__ __launch_bounds__(256) void node_mfma(
    const short* __restrict__ out_bf, float* __restrict__ agg,
    const int* __restrict__ counts,
    const float* __restrict__ root_w, const float* __restrict__ conv_b,
    const float* __restrict__ gwih, const float* __restrict__ gwhh,
    const float* __restrict__ gbih, const float* __restrict__ gbhh,
    float* __restrict__ out, short* __restrict__ out_bf_w,
    float* __restrict__ out_dup, int N)
{
  __shared__ short XH[64*128];
  __shared__ short rootT[64*64];
  __shared__ short Wih_s[192*64];
  __shared__ short Whh_s[192*64];
  __shared__ float rdeg_s[64];
  __shared__ float cb_s[64];

  int tid = threadIdx.x;
  int blk = blockIdx.x;
  int nbase = blk*64;

  {
    int n = tid >> 2, cq = tid & 3;
    int ng = nbase + n;
    short8_t v0 = {0,0,0,0,0,0,0,0}, v1 = v0;
    if (ng < N){
      const short* p = out_bf + (size_t)ng*64;
      v0 = *(const short8_t*)(p + cq*16);
      v1 = *(const short8_t*)(p + cq*16 + 8);
    }
    int c0 = 8 + cq*2;
    *(short8_t*)(XH + n*128 + ((c0     ^ (n & 7))*8)) = v0;
    *(short8_t*)(XH + n*128 + (((c0+1) ^ (n & 7))*8)) = v1;
  }
  {
    int i = tid >> 2, dq = tid & 3;
    #pragma unroll
    for (int j = 0; j < 16; ++j){
      int d = dq*16 + j;
      short v = f2bf(root_w[i*64 + d]);
      rootT[d*64 + (((i >> 3) ^ (d & 7))*8) + (i & 7)] = v;
    }
  }
  if (tid < 192){
    int g = tid;
    short pk[8];
    #pragma unroll
    for (int c = 0; c < 8; ++c){
      #pragma unroll
      for (int j = 0; j < 8; ++j) pk[j] = f2bf(gwih[g*64 + c*8 + j]);
      *(short8_t*)(Wih_s + g*64 + ((c ^ (g & 7))*8)) = *(short8_t*)&pk[0];
    }
    #pragma unroll
    for (int c = 0; c < 8; ++c){
      #pragma unroll
      for (int j = 0; j < 8; ++j) pk[j] = f2bf(gwhh[g*64 + c*8 + j]);
      *(short8_t*)(Whh_s + g*64 + ((c ^ (g & 7))*8)) = *(short8_t*)&pk[0];
    }
  }
  if (tid < 64){
    int ng = nbase + tid;
    int c = (ng < N) ? counts[ng] : 1;
    rdeg_s[tid] = 1.0f / fmaxf((float)c, 1.0f);
    cb_s[tid] = conv_b[tid];
  }
  __syncthreads();

  int lane = tid & 63, wid = tid >> 6;
  int r = lane & 15, q4 = lane >> 4;

  {
    int mh = (wid >> 1)*32, nh = (wid & 1)*32;
    f32x4_t z4 = {0.f,0.f,0.f,0.f};
    f32x4_t c00 = z4, c01 = z4, c10 = z4, c11 = z4;
    #pragma unroll
    for (int ks = 0; ks < 2; ++ks){
      int ck = 8 + ks*4 + q4;
      int swA = (ck ^ (r & 7))*8;
      int swB = ((ks*4 + q4) ^ (r & 7))*8;
      short8_t a0 = *(const short8_t*)(XH + (mh + r)*128 + swA);
      short8_t a1 = *(const short8_t*)(XH + (mh + 16 + r)*128 + swA);
      short8_t b0 = *(const short8_t*)(rootT + (nh + r)*64 + swB);
      short8_t b1 = *(const short8_t*)(rootT + (nh + 16 + r)*64 + swB);
      c00 = MFMA16(a0, b0, c00);
      c01 = MFMA16(a0, b1, c01);
      c10 = MFMA16(a1, b0, c10);
      c11 = MFMA16(a1, b1, c11);
    }
    #pragma unroll
    for (int mm = 0; mm < 2; ++mm){
      #pragma unroll
      for (int nn = 0; nn < 2; ++nn){
        f32x4_t cc = mm == 0 ? (nn == 0 ? c00 : c01) : (nn == 0 ? c10 : c11);
        int d = nh + nn*16 + r;
        #pragma unroll
        for (int reg = 0; reg < 4; ++reg){
          int n = mh + mm*16 + q4*4 + reg;
          int ng = nbase + n;
          float av = 0.0f;
          if (ng < N){
            av = agg[(size_t)ng*64 + d];
            agg[(size_t)ng*64 + d] = 0.0f;       // pre-zero for next msg pass
          }
          float v = cc[reg] + av * rdeg_s[n] + cb_s[d];
          v = fmaxf(v, 0.0f);
          XH[n*128 + (((d >> 3) ^ (n & 7))*8) + (d & 7)] = f2bf(v);
        }
      }
    }
  }
  __syncthreads();

  f32x4_t ax[4][3], ah[4][3];
  {
    f32x4_t z4 = {0.f,0.f,0.f,0.f};
    #pragma unroll
    for (int mt = 0; mt < 4; ++mt)
      #pragma unroll
      for (int gt = 0; gt < 3; ++gt){ ax[mt][gt] = z4; ah[mt][gt] = z4; }
  }
  #pragma unroll
  for (int ks = 0; ks < 2; ++ks){
    int ckM = ks*4 + q4;
    int ckH = 8 + ks*4 + q4;
    int swM = (ckM ^ (r & 7))*8;
    int swH = (ckH ^ (r & 7))*8;
    int swB = ((ks*4 + q4) ^ (r & 7))*8;
    short8_t bx[3], bh[3];
    #pragma unroll
    for (int gt = 0; gt < 3; ++gt){
      int g = gt*64 + wid*16 + r;
      bx[gt] = *(const short8_t*)(Wih_s + g*64 + swB);
      bh[gt] = *(const short8_t*)(Whh_s + g*64 + swB);
    }
    #pragma unroll
    for (int mt = 0; mt < 4; ++mt){
      short8_t aM = *(const short8_t*)(XH + (mt*16 + r)*128 + swM);
      short8_t aH = *(const short8_t*)(XH + (mt*16 + r)*128 + swH);
      #pragma unroll
      for (int gt = 0; gt < 3; ++gt){
        ax[mt][gt] = MFMA16(aM, bx[gt], ax[mt][gt]);
        ah[mt][gt] = MFMA16(aH, bh[gt], ah[mt][gt]);
      }
    }
  }

  {
    int d = wid*16 + r;
    float bir = gbih[d],      bhr = gbhh[d];
    float biz = gbih[64 + d], bhz = gbhh[64 + d];
    float bin_ = gbih[128 + d], bhn = gbhh[128 + d];
    #pragma unroll
    for (int mt = 0; mt < 4; ++mt){
      #pragma unroll
      for (int reg = 0; reg < 4; ++reg){
        int n = mt*16 + q4*4 + reg;
        int ng = nbase + n;
        if (ng < N){
          float gxr = ax[mt][0][reg], gxz = ax[mt][1][reg], gxn = ax[mt][2][reg];
          float ghr = ah[mt][0][reg], ghz = ah[mt][1][reg], ghn = ah[mt][2][reg];
          float rr = sigmoidf_(gxr + ghr + bir + bhr);
          float zz = sigmoidf_(gxz + ghz + biz + bhz);
          float nn = tanhf(gxn + bin_ + rr*(ghn + bhn));
          float h = out[(size_t)ng*64 + d];
          float v = (1.0f - zz)*nn + zz*h;
          out[(size_t)ng*64 + d] = v;
          out_bf_w[(size_t)ng*64 + d] = f2bf(v);
          if (out_dup) out_dup[(size_t)ng*64 + d] = v;
        }
      }
    }
  }
}

// ---------- Set2Set (3 steps) + readout, 256 threads, node-parallel ----------
__global__ __launch_bounds__(256) void set2set_kernel(
    const float* __restrict__ out, const int* __restrict__ bstarts,
    const int* __restrict__ bcounts,
    const float* __restrict__ lwih, const float* __restrict__ lwhh,
    const float* __restrict__ lbih, const float* __restrict__ lbhh,
    const float* __restrict__ l1w, const float* __restrict__ l1b,
    const float* __restrict__ l2w, const float* __restrict__ l2b,
    float* __restrict__ y)
{
  int b = blockIdx.x, t = threadIdx.x;
  int lane = t & 63, wid = t >> 6;
  __shared__ float qs[128];
  __shared__ float hsl[64], hs_s[64], cs_s[64];
  __shared__ float ev[512];
  __shared__ float red[256];
  __shared__ float rpart[4][64];
  __shared__ float scal[2];

  int s0 = bstarts[b], cnt = bcounts[b];
  if (cnt > 512) cnt = 512;
  if (t < 64){ hs_s[t] = 0.f; cs_s[t] = 0.f; }
  if (t < 128) qs[t] = 0.f;
  __syncthreads();

  for (int step = 0; step < 3; ++step){
    if (t < 64) hsl[t] = hs_s[t];
    __syncthreads();
    {
      float a0 = lbih[t] + lbhh[t], a1 = 0.f, a2 = 0.f, a3 = 0.f;
      const float* wi = lwih + t*128;
      #pragma unroll
      for (int kq = 0; kq < 32; ++kq){
        float4 w4 = *(const float4*)(wi + kq*4);
        a0 = fmaf(qs[kq*4+0], w4.x, a0);
        a1 = fmaf(qs[kq*4+1], w4.y, a1);
        a2 = fmaf(qs[kq*4+2], w4.z, a2);
        a3 = fmaf(qs[kq*4+3], w4.w, a3);
      }
      const float* wh = lwhh + t*64;
      #pragma unroll
      for (int kq = 0; kq < 16; ++kq){
        float4 w4 = *(const float4*)(wh + kq*4);
        a0 = fmaf(hsl[kq*4+0], w4.x, a0);
        a1 = fmaf(hsl[kq*4+1], w4.y, a1);
        a2 = fmaf(hsl[kq*4+2], w4.z, a2);
        a3 = fmaf(hsl[kq*4+3], w4.w, a3);
      }
      red[t] = (a0 + a1) + (a2 + a3);
    }
    __syncthreads();
    if (t < 64){
      float ig = sigmoidf_(red[t]);
      float fg = sigmoidf_(red[64 + t]);
      float gg = tanhf(red[128 + t]);
      float og = sigmoidf_(red[192 + t]);
      float c = fg*cs_s[t] + ig*gg;
      cs_s[t] = c;
      hs_s[t] = og*tanhf(c);
    }
    __syncthreads();

    float lmax = -1e30f;
    for (int idx = t; idx < cnt; idx += 256){
      const float* row = out + (size_t)(s0 + idx)*64;
      float a0 = 0.f, a1 = 0.f, a2 = 0.f, a3 = 0.f;
      #pragma unroll
      for (int kq = 0; kq < 16; ++kq){
        float4 v = *(const float4*)(row + kq*4);
        a0 = fmaf(v.x, hs_s[kq*4+0], a0);
        a1 = fmaf(v.y, hs_s[kq*4+1], a1);
        a2 = fmaf(v.z, hs_s[kq*4+2], a2);
        a3 = fmaf(v.w, hs_s[kq*4+3], a3);
      }
      float acc = (a0 + a1) + (a2 + a3);
      ev[idx] = acc;
      lmax = fmaxf(lmax, acc);
    }
    red[t] = lmax;
    __syncthreads();
    #pragma unroll
    for (int off = 128; off > 0; off >>= 1){
      if (t < off) red[t] = fmaxf(red[t], red[t + off]);
      __syncthreads();
    }
    if (t == 0) scal[0] = red[0];
    __syncthreads();
    float m = scal[0];

    float ls = 0.f;
    for (int idx = t; idx < cnt; idx += 256){
      float a = expf(ev[idx] - m);
      ev[idx] = a;
      ls += a;
    }
    red[t] = ls;
    __syncthreads();
    #pragma unroll
    for (int off = 128; off > 0; off >>= 1){
      if (t < off) red[t] += red[t + off];
      __syncthreads();
    }
    if (t == 0) scal[1] = red[0];
    __syncthreads();
    float lst = scal[1];

    float part = 0.f;
    for (int idx = wid; idx < cnt; idx += 4)
      part = fmaf(ev[idx], out[(size_t)(s0 + idx)*64 + lane], part);
    rpart[wid][lane] = part;
    __syncthreads();
    if (t < 64){
      float r = (rpart[0][t] + rpart[1][t]) + (rpart[2][t] + rpart[3][t]);
      r = (cnt > 0) ? r / lst : 0.f;
      qs[t] = hs_s[t];
      qs[64 + t] = r;
    }
    __syncthreads();
  }

  if (t < 64){
    float a0 = l1b[t], a1 = 0.f, a2 = 0.f, a3 = 0.f;
    const float* w1 = l1w + t*128;
    #pragma unroll
    for (int kq = 0; kq < 32; ++kq){
      float4 w4 = *(const float4*)(w1 + kq*4);
      a0 = fmaf(qs[kq*4+0], w4.x, a0);
      a1 = fmaf(qs[kq*4+1], w4.y, a1);
      a2 = fmaf(qs[kq*4+2], w4.z, a2);
      a3 = fmaf(qs[kq*4+3], w4.w, a3);
    }
    float acc = (a0 + a1) + (a2 + a3);
    float v = fmaxf(acc, 0.0f) * l2w[t];
    #pragma unroll
    for (int off = 32; off > 0; off >>= 1) v += __shfl_xor(v, off, 64);
    if (t == 0) y[b] = v + l2b[0];
  }
}

extern "C" void kernel_launch(void* const* d_in, const int* in_sizes, int n_in,
                              void* d_out, int out_size, void* d_ws, size_t ws_size,
                              hipStream_t stream){
  const float* x      = (const float*)d_in[0];
  const int*   ei     = (const int*)  d_in[1];
  const float* ea     = (const float*)d_in[2];
  const int*   batch  = (const int*)  d_in[3];
  const float* lin0_w = (const float*)d_in[4];
  const float* lin0_b = (const float*)d_in[5];
  const float* nn1_w  = (const float*)d_in[6];
  const float* nn1_b  = (const float*)d_in[7];
  const float* nn2_w  = (const float*)d_in[8];
  const float* nn2_b  = (const float*)d_in[9];
  const float* root_w = (const float*)d_in[10];
  const float* conv_b = (const float*)d_in[11];
  const float* gwih   = (const float*)d_in[12];
  const float* gwhh   = (const float*)d_in[13];
  const float* gbih   = (const float*)d_in[14];
  const float* gbhh   = (const float*)d_in[15];
  const float* lwih   = (const float*)d_in[16];
  const float* lwhh   = (const float*)d_in[17];
  const float* lbih   = (const float*)d_in[18];
  const float* lbhh   = (const float*)d_in[19];
  const float* l1w    = (const float*)d_in[20];
  const float* l1b    = (const float*)d_in[21];
  const float* l2w    = (const float*)d_in[22];
  const float* l2b    = (const float*)d_in[23];

  const int N = in_sizes[0] / 14;
  const int E = in_sizes[1] / 2;
  const int B = NBG;
  const int* src  = ei;
  const int* dstv = ei + E;

  char* wsp = (char*)d_ws; size_t off = 0;
  auto alloc = [&](size_t bytes)->char* {
    char* p = wsp + off; off += (bytes + 255) & ~((size_t)255); return p;
  };
  float* out     = (float*)alloc((size_t)N*64*4);
  short* out_bf  = (short*)alloc((size_t)N*64*2);
  float* agg     = (float*)alloc((size_t)N*64*4);
  int*   counts  = (int*)  alloc((size_t)N*4);
  int*   bcounts = (int*)  alloc((size_t)B*4);   // contiguous with counts
  int*   starts  = (int*)  alloc((size_t)N*4);
  int*   cursor  = (int*)  alloc((size_t)N*4);
  int*   sorted  = (int*)  alloc((size_t)E*4);
  int*   bstarts = (int*)  alloc((size_t)B*4);
  int*   bcursor = (int*)  alloc((size_t)B*4);
  short* hid_bf  = (short*)alloc((size_t)E*128*2);
  short* W2t     = (short*)alloc((size_t)64*KP*2);

  lin0_kernel<<<N, 64, 0, stream>>>(x, lin0_w, lin0_b, out, out_bf, N);
  ehid_kernel<<<E, 128, 0, stream>>>(ea, nn1_w, nn1_b, hid_bf, E);

  size_t cspan = (((size_t)N*4 + 255) & ~(size_t)255) + (size_t)B*4;
  hipMemsetAsync(counts, 0, cspan, stream);
  count2_kernel<<<(E + N + 255)/256, 256, 0, stream>>>(dstv, E, batch, N, counts, bcounts);
  scan2_kernel<<<2, 1024, 0, stream>>>(counts, starts, cursor, N,
                                       bcounts, bstarts, bcursor, B);
  scatter_kernel<<<(E + 255)/256, 256, 0, stream>>>(dstv, cursor, sorted, E);

  w2t_build<<<64, 256, 0, stream>>>(nn2_w, nn2_b, W2t);
  hipMemsetAsync(agg, 0, (size_t)N*64*4, stream);

  int mblocks = (E + 127)/128;
  int nblocks = (N + 63)/64;
  dim3 mg(mblocks, 4);
  for (int it = 0; it < 3; ++it){
    msg_gemm3<<<mg, 256, 0, stream>>>(out_bf, hid_bf, W2t, sorted, src, dstv, agg, E);
    node_mfma<<<nblocks, 256, 0, stream>>>(out_bf, agg, counts, root_w, conv_b,
                                           gwih, gwhh, gbih, gbhh, out, out_bf,
                                           (it == 2) ? ((float*)d_out + 300) : nullptr, N);
  }

  set2set_kernel<<<B, 256, 0, stream>>>(out, bstarts, bcounts, lwih, lwhh, lbih, lbhh,
                                        l1w, l1b, l2w, l2b, (float*)d_out);
}